// Round 20
// baseline (893.645 us; speedup 1.0000x reference)
//
#include <hip/hip_runtime.h>
#include <math.h>

#define D 128
#define TILE 64
#define ESP 136   // es row stride (ushorts)

typedef __attribute__((ext_vector_type(8))) short s16x8;  // 8 bf16 (4 VGPRs)
typedef __attribute__((ext_vector_type(4))) float f32x4;  // MFMA accumulator

__device__ inline ushort f32_to_bf16(float x) {
    unsigned u = __float_as_uint(x);
    return (ushort)((u + 0x7fff + ((u >> 16) & 1)) >> 16);   // RNE
}
__device__ inline float bf16_to_f32(ushort h) {
    return __uint_as_float(((unsigned)h) << 16);
}

// ---------------- zero stats (512 f) + degree (N ints) ----------------
__global__ void zero_misc_k(float* stats, int* deg, int n) {
    int i = blockIdx.x * blockDim.x + threadIdx.x;
    if (i < 512) stats[i] = 0.f;
    if (i < n) deg[i] = 0;
}

// ---------------- weight prep: pack 5 weights into MFMA B-frag layout ----------------
// F[((wsel*32 + s*8 + t)*64 + l)*8 + j] = W[t*16 + (l&15)][s*32 + (l>>4)*8 + j]
__global__ void wconv5_k(const float* __restrict__ W0, const float* __restrict__ W1,
                         const float* __restrict__ W2, const float* __restrict__ W3,
                         const float* __restrict__ W4,
                         ushort* __restrict__ Fh, ushort* __restrict__ Fl) {
    int i = blockIdx.x * blockDim.x + threadIdx.x;
    if (i >= 5 * 16384) return;
    int wsel = i >> 14;
    int rem = i & 16383;
    int j = rem & 7;
    int l = (rem >> 3) & 63;
    int st = rem >> 9;             // s*8 + t
    int s = st >> 3, t = st & 7;
    int l15 = l & 15, lk = l >> 4;
    const float* W = wsel == 0 ? W0 : wsel == 1 ? W1 : wsel == 2 ? W2 : wsel == 3 ? W3 : W4;
    float x = W[(size_t)(t * 16 + l15) * D + s * 32 + lk * 8 + j];
    ushort h = f32_to_bf16(x);
    Fh[i] = h;
    Fl[i] = f32_to_bf16(x - bf16_to_f32(h));
}

// ---------------- K1: fused node linear via split-bf16 MFMA ----------------
__global__ __launch_bounds__(256, 4)
void node_linear_k(const float* __restrict__ h_in,
                   const ushort* __restrict__ Fh, const ushort* __restrict__ Fl,
                   const float* __restrict__ Ub, const float* __restrict__ Vb,
                   const float* __restrict__ Bb, const float* __restrict__ Cb,
                   float* __restrict__ outU, ushort* __restrict__ outV,
                   ushort* __restrict__ outB, ushort* __restrict__ outC,
                   int M)
{
    const int tid = threadIdx.x;
    const int w = tid >> 6, l = tid & 63;
    const int l15 = l & 15, lk = l >> 4;
    const int row0 = blockIdx.x * TILE;

    s16x8 ahs[4], als[4];
    {
        int arow = row0 + w * 16 + l15;
        if (arow >= M) arow = M - 1;
        const float* hr = h_in + (size_t)arow * D;
        #pragma unroll
        for (int s = 0; s < 4; ++s) {
            f32x4 x0 = *reinterpret_cast<const f32x4*>(hr + s * 32 + lk * 8);
            f32x4 x1 = *reinterpret_cast<const f32x4*>(hr + s * 32 + lk * 8 + 4);
            s16x8 h, lo;
            #pragma unroll
            for (int j = 0; j < 4; ++j) {
                ushort hb = f32_to_bf16(x0[j]);
                h[j] = (short)hb;
                lo[j] = (short)f32_to_bf16(x0[j] - bf16_to_f32(hb));
                ushort hb2 = f32_to_bf16(x1[j]);
                h[j + 4] = (short)hb2;
                lo[j + 4] = (short)f32_to_bf16(x1[j] - bf16_to_f32(hb2));
            }
            ahs[s] = h; als[s] = lo;
        }
    }

    const int mrow0 = row0 + w * 16 + lk * 4;

    #pragma unroll
    for (int wsel = 0; wsel < 4; ++wsel) {
        f32x4 acc[8];
        #pragma unroll
        for (int n = 0; n < 8; ++n) acc[n] = (f32x4){0.f, 0.f, 0.f, 0.f};

        #pragma unroll
        for (int s = 0; s < 4; ++s) {
            #pragma unroll
            for (int t = 0; t < 8; ++t) {
                size_t fo = ((size_t)((wsel * 32 + s * 8 + t) * 64 + l)) * 8;
                s16x8 bh = *reinterpret_cast<const s16x8*>(Fh + fo);
                s16x8 bl = *reinterpret_cast<const s16x8*>(Fl + fo);
                acc[t] = __builtin_amdgcn_mfma_f32_16x16x32_bf16(ahs[s], bh, acc[t], 0, 0, 0);
                acc[t] = __builtin_amdgcn_mfma_f32_16x16x32_bf16(ahs[s], bl, acc[t], 0, 0, 0);
                acc[t] = __builtin_amdgcn_mfma_f32_16x16x32_bf16(als[s], bh, acc[t], 0, 0, 0);
                if ((t & 1) == 1 && t < 7) __builtin_amdgcn_sched_barrier(0);
            }
        }

        const float* bias = wsel == 0 ? Ub : wsel == 1 ? Vb : wsel == 2 ? Bb : Cb;
        float bv[8];
        #pragma unroll
        for (int n = 0; n < 8; ++n) bv[n] = bias[n * 16 + l15];
        #pragma unroll
        for (int r = 0; r < 4; ++r) {
            int row = mrow0 + r;
            if (row < M) {
                if (wsel == 0) {
                    float* orow = outU + (size_t)row * D;
                    #pragma unroll
                    for (int n = 0; n < 8; ++n)
                        orow[n * 16 + l15] = acc[n][r] + bv[n];
                } else {
                    ushort* orow = (wsel == 1 ? outV : wsel == 2 ? outB : outC) + (size_t)row * D;
                    #pragma unroll
                    for (int n = 0; n < 8; ++n)
                        orow[n * 16 + l15] = f32_to_bf16(acc[n][r] + bv[n]);
                }
            }
        }
    }
}

// ---------------- counting sort: histogram / scan / scatter ----------------
__global__ void hist_k(const int* __restrict__ dst, int* __restrict__ deg, int E) {
    for (int e = blockIdx.x * blockDim.x + threadIdx.x; e < E; e += gridDim.x * blockDim.x)
        atomicAdd(&deg[dst[e]], 1);
}

__global__ void scan_k(const int* __restrict__ deg, int* __restrict__ off,
                       int* __restrict__ cursor, int n)
{
    __shared__ int wsum[16], wpre[16];
    const int tid = threadIdx.x, lane = tid & 63, w = tid >> 6;
    int carry = 0;  // live only in thread 0
    for (int base = 0; base < n; base += 1024) {
        int i = base + tid;
        int v = (i < n) ? deg[i] : 0;
        int x = v;
        #pragma unroll
        for (int d = 1; d < 64; d <<= 1) {
            int t = __shfl_up(x, d);
            if (lane >= d) x += t;
        }
        if (lane == 63) wsum[w] = x;
        __syncthreads();
        if (tid == 0) {
            int run = carry;
            #pragma unroll
            for (int j = 0; j < 16; ++j) { int t = wsum[j]; wpre[j] = run; run += t; }
            carry = run;
        }
        __syncthreads();
        int excl = wpre[w] + x - v;
        if (i < n) { off[i] = excl; cursor[i] = excl; }
    }
    if (tid == 0) off[n] = carry;
}

__global__ void scatter_k(const int* __restrict__ dst, int* __restrict__ cursor,
                          int* __restrict__ perm, int E)
{
    for (int e = blockIdx.x * blockDim.x + threadIdx.x; e < E; e += gridDim.x * blockDim.x) {
        int pos = atomicAdd(&cursor[dst[e]], 1);
        perm[pos] = e;
    }
}

// ---------------- K2: edge kernel, split-bf16 MFMA ----------------
// 6 waves/SIMD (cap 85): occupancy is edge_k's only binding constraint
// (R18/R19 proved time-insensitivity to traffic). Dieted structure from R18.
__global__ __launch_bounds__(256, 6)
void edge_k(const float* __restrict__ e_in,
            const int* __restrict__ eidx,   // [2][E] int32: dst then src
            const int* __restrict__ perm,   // edge ids sorted by dst
            const ushort* __restrict__ AFh, const ushort* __restrict__ AFl,
            const float* __restrict__ Ab,
            const ushort* __restrict__ Vh, const ushort* __restrict__ Bh,
            const ushort* __restrict__ Ch,
            float* __restrict__ out_h, float* __restrict__ out_e,
            float* __restrict__ e_sum, float* __restrict__ e_sq,
            int E)
{
    __shared__ int eids[TILE], dns[TILE], sns[TILE];
    __shared__ ushort es[TILE * ESP];     // bf16 e_in tile (wave-private spans)
    __shared__ float sbuf[512], qbuf[512];

    const int tid = threadIdx.x;
    const int w = tid >> 6;
    const int l = tid & 63;
    const int l15 = l & 15;
    const int lk = l >> 4;
    const int e0 = blockIdx.x * TILE;

    if (tid < TILE) {
        int e = e0 + tid;
        int ec = e < E ? e : E - 1;
        int eid = perm[ec];
        eids[tid] = eid;
        dns[tid] = eidx[eid];
        sns[tid] = eidx[(size_t)E + eid];
    }
    __syncthreads();

    f32x4 acc[8];
    #pragma unroll
    for (int n = 0; n < 8; ++n) acc[n] = (f32x4){0.f, 0.f, 0.f, 0.f};

    {
        const int arow = w * 16 + l15;
        const float* er = e_in + (size_t)eids[arow] * D;
        #pragma unroll
        for (int s = 0; s < 4; ++s) {
            f32x4 x0 = __builtin_nontemporal_load(
                reinterpret_cast<const f32x4*>(er + s * 32 + lk * 8));
            f32x4 x1 = __builtin_nontemporal_load(
                reinterpret_cast<const f32x4*>(er + s * 32 + lk * 8 + 4));
            s16x8 ah, al;
            #pragma unroll
            for (int j = 0; j < 4; ++j) {
                ushort hb = f32_to_bf16(x0[j]);
                ah[j] = (short)hb;
                al[j] = (short)f32_to_bf16(x0[j] - bf16_to_f32(hb));
                ushort hb2 = f32_to_bf16(x1[j]);
                ah[j + 4] = (short)hb2;
                al[j + 4] = (short)f32_to_bf16(x1[j] - bf16_to_f32(hb2));
            }
            *reinterpret_cast<s16x8*>(&es[arow * ESP + s * 32 + lk * 8]) = ah;
            #pragma unroll
            for (int t = 0; t < 8; ++t) {
                size_t fo = ((size_t)((s * 8 + t) * 64 + l)) * 8;
                s16x8 bh = *reinterpret_cast<const s16x8*>(AFh + fo);
                s16x8 bl = *reinterpret_cast<const s16x8*>(AFl + fo);
                acc[t] = __builtin_amdgcn_mfma_f32_16x16x32_bf16(ah, bh, acc[t], 0, 0, 0);
                acc[t] = __builtin_amdgcn_mfma_f32_16x16x32_bf16(ah, bl, acc[t], 0, 0, 0);
                acc[t] = __builtin_amdgcn_mfma_f32_16x16x32_bf16(al, bh, acc[t], 0, 0, 0);
                if ((t & 1) == 1 && t < 7) __builtin_amdgcn_sched_barrier(0);
            }
        }
    }

    // epilogue in frag layout, TWO n-halves; fence only every 2nd row-iter.
    const int mrow0 = w * 16 + lk * 4;
    #pragma unroll
    for (int h = 0; h < 2; ++h) {
        float abv[4], sst[4], sq[4], rs[4];
        #pragma unroll
        for (int n = 0; n < 4; ++n) {
            abv[n] = Ab[(h * 4 + n) * 16 + l15];
            sst[n] = 0.f; sq[n] = 0.f; rs[n] = 0.f;
        }
        #pragma unroll
        for (int r = 0; r < 4; ++r) {
            int row = mrow0 + r;
            int eid = eids[row], dn = dns[row], sn = sns[row];
            bool valid = (e0 + row) < E;
            if (valid) {
                const ushort* br = Bh + (size_t)dn * D;
                const ushort* cr = Ch + (size_t)sn * D;
                float* oe = out_e + (size_t)eid * D;
                #pragma unroll
                for (int n = 0; n < 4; ++n) {
                    int col = (h * 4 + n) * 16 + l15;
                    float pre = acc[h * 4 + n][r] + abv[n]
                              + bf16_to_f32(br[col]) + bf16_to_f32(cr[col]);
                    __builtin_nontemporal_store(pre, oe + col);
                    sst[n] += pre;
                    sq[n] += pre * pre;
                }
            }
            const ushort* vr = Vh + (size_t)sn * D;
            #pragma unroll
            for (int n = 0; n < 4; ++n) {
                int col = (h * 4 + n) * 16 + l15;
                float ein = bf16_to_f32(es[row * ESP + col]);
                float m = valid ? bf16_to_f32(vr[col]) / (1.f + __expf(-ein)) : 0.f;
                rs[n] += m;
            }
            bool flush = (r == 3) || (dns[row + 1] != dn);
            if (flush) {
                float* dst = out_h + (size_t)dn * D;
                #pragma unroll
                for (int n = 0; n < 4; ++n) {
                    unsafeAtomicAdd(dst + (h * 4 + n) * 16 + l15, rs[n]);
                    rs[n] = 0.f;
                }
            }
            if (r & 1) __builtin_amdgcn_sched_barrier(0);
        }
        #pragma unroll
        for (int n = 0; n < 4; ++n) {
            sst[n] += __shfl_xor(sst[n], 16); sst[n] += __shfl_xor(sst[n], 32);
            sq[n]  += __shfl_xor(sq[n], 16);  sq[n]  += __shfl_xor(sq[n], 32);
        }
        if (l < 16) {
            #pragma unroll
            for (int n = 0; n < 4; ++n) {
                sbuf[w * 128 + (h * 4 + n) * 16 + l] = sst[n];
                qbuf[w * 128 + (h * 4 + n) * 16 + l] = sq[n];
            }
        }
    }
    __syncthreads();
    if (tid < 128) {
        float ss = sbuf[tid] + sbuf[128 + tid] + sbuf[256 + tid] + sbuf[384 + tid];
        float qq = qbuf[tid] + qbuf[128 + tid] + qbuf[256 + tid] + qbuf[384 + tid];
        unsafeAtomicAdd(&e_sum[tid], ss);
        unsafeAtomicAdd(&e_sq[tid], qq);
    }
}

// ---------------- col stats over a [rows x 128] matrix (float4) ----------------
__global__ void col_stats_k(const float* __restrict__ X, int rows,
                            float* __restrict__ sum, float* __restrict__ sumsq)
{
    __shared__ float sr[8][128], qr[8][128];
    const int tx = threadIdx.x & 31;
    const int rp = threadIdx.x >> 5;
    float4 s = make_float4(0.f, 0.f, 0.f, 0.f);
    float4 q = make_float4(0.f, 0.f, 0.f, 0.f);
    for (int r = blockIdx.x * 8 + rp; r < rows; r += gridDim.x * 8) {
        float4 v = *reinterpret_cast<const float4*>(X + (size_t)r * D + 4 * tx);
        s.x += v.x; q.x += v.x * v.x;
        s.y += v.y; q.y += v.y * v.y;
        s.z += v.z; q.z += v.z * v.z;
        s.w += v.w; q.w += v.w * v.w;
    }
    *reinterpret_cast<float4*>(&sr[rp][4 * tx]) = s;
    *reinterpret_cast<float4*>(&qr[rp][4 * tx]) = q;
    __syncthreads();
    if (threadIdx.x < 128) {
        float ss = 0.f, qq = 0.f;
        #pragma unroll
        for (int t = 0; t < 8; ++t) { ss += sr[t][threadIdx.x]; qq += qr[t][threadIdx.x]; }
        unsafeAtomicAdd(&sum[threadIdx.x], ss);
        unsafeAtomicAdd(&sumsq[threadIdx.x], qq);
    }
}

// ---------------- finalize: in-place BN + ReLU + residual (float4) ----------------
__global__ void finalize_k(const float* __restrict__ res_in,
                           float* __restrict__ out,
                           const float* __restrict__ sum, const float* __restrict__ sumsq,
                           const float* __restrict__ gamma, const float* __restrict__ beta,
                           float cntInv, int rows)
{
    const int tx = threadIdx.x & 31;
    const int rp = threadIdx.x >> 5;
    const int col4 = 4 * tx;
    float mu[4], g[4], b[4];
    #pragma unroll
    for (int i = 0; i < 4; ++i) {
        float m = sum[col4 + i] * cntInv;
        float var = sumsq[col4 + i] * cntInv - m * m;
        mu[i] = m;
        g[i] = gamma[col4 + i] * rsqrtf(var + 1e-5f);
        b[i] = beta[col4 + i];
    }
    for (int r = blockIdx.x * 8 + rp; r < rows; r += gridDim.x * 8) {
        size_t o = (size_t)r * D + col4;
        float4 x = *reinterpret_cast<const float4*>(out + o);
        float4 rr = *reinterpret_cast<const float4*>(res_in + o);
        float4 y;
        y.x = rr.x + fmaxf(g[0] * (x.x - mu[0]) + b[0], 0.f);
        y.y = rr.y + fmaxf(g[1] * (x.y - mu[1]) + b[1], 0.f);
        y.z = rr.z + fmaxf(g[2] * (x.z - mu[2]) + b[2], 0.f);
        y.w = rr.w + fmaxf(g[3] * (x.w - mu[3]) + b[3], 0.f);
        *reinterpret_cast<float4*>(out + o) = y;
    }
}

extern "C" void kernel_launch(void* const* d_in, const int* in_sizes, int n_in,
                              void* d_out, int out_size, void* d_ws, size_t ws_size,
                              hipStream_t stream)
{
    const float* h_in = (const float*)d_in[0];
    const float* e_in = (const float*)d_in[1];
    const int*   eidx = (const int*)d_in[2];
    const float* Uw = (const float*)d_in[3];  const float* Ub = (const float*)d_in[4];
    const float* Vw = (const float*)d_in[5];  const float* Vb = (const float*)d_in[6];
    const float* Aw = (const float*)d_in[7];  const float* Ab = (const float*)d_in[8];
    const float* Bw = (const float*)d_in[9];  const float* Bb = (const float*)d_in[10];
    const float* Cw = (const float*)d_in[11]; const float* Cb = (const float*)d_in[12];
    const float* hg = (const float*)d_in[13]; const float* hb = (const float*)d_in[14];
    const float* eg = (const float*)d_in[15]; const float* eb = (const float*)d_in[16];

    const int N = in_sizes[0] / D;
    const int E = in_sizes[1] / D;

    float* out_h = (float*)d_out;
    float* out_e = out_h + (size_t)N * D;

    // workspace: bf16 tables first, then stats/sort/frag buffers
    ushort* Vh16 = (ushort*)d_ws;
    ushort* Bh16 = Vh16 + (size_t)N * D;
    ushort* Ch16 = Bh16 + (size_t)N * D;
    float* stats = (float*)(Ch16 + (size_t)N * D);
    float* h_sum = stats;       float* h_sq = stats + 128;
    float* e_sum = stats + 256; float* e_sq = stats + 384;
    int* deg    = (int*)(stats + 512);
    int* off    = deg + N;
    int* cursor = off + N + 1;
    int* perm   = cursor + N;
    ushort* Fh = (ushort*)(perm + E);        // 5*16384 ushort
    ushort* Fl = Fh + 5 * 16384;

    zero_misc_k<<<(N + 255) / 256, 256, 0, stream>>>(stats, deg, N);
    wconv5_k<<<(5 * 16384 + 255) / 256, 256, 0, stream>>>(Uw, Vw, Bw, Cw, Aw, Fh, Fl);
    hist_k<<<1024, 256, 0, stream>>>(eidx, deg, E);
    scan_k<<<1, 1024, 0, stream>>>(deg, off, cursor, N);
    scatter_k<<<1024, 256, 0, stream>>>(eidx, cursor, perm, E);
    node_linear_k<<<(N + TILE - 1) / TILE, 256, 0, stream>>>(
        h_in, Fh, Fl, Ub, Vb, Bb, Cb, out_h, Vh16, Bh16, Ch16, N);
    edge_k<<<(E + TILE - 1) / TILE, 256, 0, stream>>>(
        e_in, eidx, perm, Fh + 4 * 16384, Fl + 4 * 16384, Ab, Vh16, Bh16, Ch16,
        out_h, out_e, e_sum, e_sq, E);
    col_stats_k<<<256, 256, 0, stream>>>(out_h, N, h_sum, h_sq);
    finalize_k<<<256, 256, 0, stream>>>(h_in, out_h, h_sum, h_sq, hg, hb, 1.0f / (float)N, N);
    finalize_k<<<2048, 256, 0, stream>>>(e_in, out_e, e_sum, e_sq, eg, eb, 1.0f / (float)E, E);
}

// Round 21
// 865.514 us; speedup vs baseline: 1.0325x; 1.0325x over previous
//
#include <hip/hip_runtime.h>
#include <hip/hip_bf16.h>
#include <math.h>

#define D 128
#define TILE 64
#define ESP 136   // es row stride (ushorts)

typedef __attribute__((ext_vector_type(8))) short s16x8;  // 8 bf16 (4 VGPRs)
typedef __attribute__((ext_vector_type(4))) float f32x4;  // MFMA accumulator

__device__ inline ushort f2bf(float x) {   // RNE via v_cvt (pairs fuse to cvt_pk)
    __hip_bfloat16 h = __float2bfloat16(x);
    return *reinterpret_cast<ushort*>(&h);
}
__device__ inline float bf16_to_f32(ushort h) {
    return __uint_as_float(((unsigned)h) << 16);
}

// convert 8 floats -> hi/lo bf16 frags
__device__ inline void cvt_hilo(f32x4 x0, f32x4 x1, s16x8& ah, s16x8& al) {
    #pragma unroll
    for (int j = 0; j < 4; ++j) {
        ushort hb = f2bf(x0[j]);
        ah[j] = (short)hb;
        al[j] = (short)f2bf(x0[j] - bf16_to_f32(hb));
        ushort hb2 = f2bf(x1[j]);
        ah[j + 4] = (short)hb2;
        al[j + 4] = (short)f2bf(x1[j] - bf16_to_f32(hb2));
    }
}

// ---------------- zero stats (512 f) + degree (N ints) ----------------
__global__ void zero_misc_k(float* stats, int* deg, int n) {
    int i = blockIdx.x * blockDim.x + threadIdx.x;
    if (i < 512) stats[i] = 0.f;
    if (i < n) deg[i] = 0;
}

// ---------------- weight prep: pack 5 weights into MFMA B-frag layout ----------------
// F[((wsel*32 + s*8 + t)*64 + l)*8 + j] = W[t*16 + (l&15)][s*32 + (l>>4)*8 + j]
__global__ void wconv5_k(const float* __restrict__ W0, const float* __restrict__ W1,
                         const float* __restrict__ W2, const float* __restrict__ W3,
                         const float* __restrict__ W4,
                         ushort* __restrict__ Fh, ushort* __restrict__ Fl) {
    int i = blockIdx.x * blockDim.x + threadIdx.x;
    if (i >= 5 * 16384) return;
    int wsel = i >> 14;
    int rem = i & 16383;
    int j = rem & 7;
    int l = (rem >> 3) & 63;
    int st = rem >> 9;             // s*8 + t
    int s = st >> 3, t = st & 7;
    int l15 = l & 15, lk = l >> 4;
    const float* W = wsel == 0 ? W0 : wsel == 1 ? W1 : wsel == 2 ? W2 : wsel == 3 ? W3 : W4;
    float x = W[(size_t)(t * 16 + l15) * D + s * 32 + lk * 8 + j];
    ushort h = f2bf(x);
    Fh[i] = h;
    Fl[i] = f2bf(x - bf16_to_f32(h));
}

// ---------------- K1: fused node linear via split-bf16 MFMA ----------------
__global__ __launch_bounds__(256, 4)
void node_linear_k(const float* __restrict__ h_in,
                   const ushort* __restrict__ Fh, const ushort* __restrict__ Fl,
                   const float* __restrict__ Ub, const float* __restrict__ Vb,
                   const float* __restrict__ Bb, const float* __restrict__ Cb,
                   float* __restrict__ outU, ushort* __restrict__ outV,
                   ushort* __restrict__ outB, ushort* __restrict__ outC,
                   int M)
{
    const int tid = threadIdx.x;
    const int w = tid >> 6, l = tid & 63;
    const int l15 = l & 15, lk = l >> 4;
    const int row0 = blockIdx.x * TILE;

    s16x8 ahs[4], als[4];
    {
        int arow = row0 + w * 16 + l15;
        if (arow >= M) arow = M - 1;
        const float* hr = h_in + (size_t)arow * D;
        #pragma unroll
        for (int s = 0; s < 4; ++s) {
            f32x4 x0 = *reinterpret_cast<const f32x4*>(hr + s * 32 + lk * 8);
            f32x4 x1 = *reinterpret_cast<const f32x4*>(hr + s * 32 + lk * 8 + 4);
            cvt_hilo(x0, x1, ahs[s], als[s]);
        }
    }

    const int mrow0 = row0 + w * 16 + lk * 4;

    #pragma unroll
    for (int wsel = 0; wsel < 4; ++wsel) {
        f32x4 acc[8];
        #pragma unroll
        for (int n = 0; n < 8; ++n) acc[n] = (f32x4){0.f, 0.f, 0.f, 0.f};

        #pragma unroll
        for (int s = 0; s < 4; ++s) {
            #pragma unroll
            for (int t = 0; t < 8; ++t) {
                size_t fo = ((size_t)((wsel * 32 + s * 8 + t) * 64 + l)) * 8;
                s16x8 bh = *reinterpret_cast<const s16x8*>(Fh + fo);
                s16x8 bl = *reinterpret_cast<const s16x8*>(Fl + fo);
                acc[t] = __builtin_amdgcn_mfma_f32_16x16x32_bf16(ahs[s], bh, acc[t], 0, 0, 0);
                acc[t] = __builtin_amdgcn_mfma_f32_16x16x32_bf16(ahs[s], bl, acc[t], 0, 0, 0);
                acc[t] = __builtin_amdgcn_mfma_f32_16x16x32_bf16(als[s], bh, acc[t], 0, 0, 0);
                if ((t & 1) == 1 && t < 7) __builtin_amdgcn_sched_barrier(0);
            }
        }

        const float* bias = wsel == 0 ? Ub : wsel == 1 ? Vb : wsel == 2 ? Bb : Cb;
        float bv[8];
        #pragma unroll
        for (int n = 0; n < 8; ++n) bv[n] = bias[n * 16 + l15];
        #pragma unroll
        for (int r = 0; r < 4; ++r) {
            int row = mrow0 + r;
            if (row < M) {
                if (wsel == 0) {
                    float* orow = outU + (size_t)row * D;
                    #pragma unroll
                    for (int n = 0; n < 8; ++n)
                        orow[n * 16 + l15] = acc[n][r] + bv[n];
                } else {
                    ushort* orow = (wsel == 1 ? outV : wsel == 2 ? outB : outC) + (size_t)row * D;
                    #pragma unroll
                    for (int n = 0; n < 8; ++n)
                        orow[n * 16 + l15] = f2bf(acc[n][r] + bv[n]);
                }
            }
        }
    }
}

// ---------------- counting sort: histogram / scan / scatter ----------------
__global__ void hist_k(const int* __restrict__ dst, int* __restrict__ deg, int E) {
    for (int e = blockIdx.x * blockDim.x + threadIdx.x; e < E; e += gridDim.x * blockDim.x)
        atomicAdd(&deg[dst[e]], 1);
}

__global__ void scan_k(const int* __restrict__ deg, int* __restrict__ off,
                       int* __restrict__ cursor, int n)
{
    __shared__ int wsum[16], wpre[16];
    const int tid = threadIdx.x, lane = tid & 63, w = tid >> 6;
    int carry = 0;  // live only in thread 0
    for (int base = 0; base < n; base += 1024) {
        int i = base + tid;
        int v = (i < n) ? deg[i] : 0;
        int x = v;
        #pragma unroll
        for (int d = 1; d < 64; d <<= 1) {
            int t = __shfl_up(x, d);
            if (lane >= d) x += t;
        }
        if (lane == 63) wsum[w] = x;
        __syncthreads();
        if (tid == 0) {
            int run = carry;
            #pragma unroll
            for (int j = 0; j < 16; ++j) { int t = wsum[j]; wpre[j] = run; run += t; }
            carry = run;
        }
        __syncthreads();
        int excl = wpre[w] + x - v;
        if (i < n) { off[i] = excl; cursor[i] = excl; }
    }
    if (tid == 0) off[n] = carry;
}

__global__ void scatter_k(const int* __restrict__ dst, int* __restrict__ cursor,
                          int* __restrict__ perm, int E)
{
    for (int e = blockIdx.x * blockDim.x + threadIdx.x; e < E; e += gridDim.x * blockDim.x) {
        int pos = atomicAdd(&cursor[dst[e]], 1);
        perm[pos] = e;
    }
}

// ---------------- K2: edge kernel, split-bf16 MFMA ----------------
// 2-stage pipeline on the e_in loads (step s+1 issued before step s's
// convert+MFMA block -> only one HBM latency exposed per wave) + native
// v_cvt bf16 conversion. 5 waves/SIMD (cap 96; natural ~88 with pipeline).
__global__ __launch_bounds__(256, 5)
void edge_k(const float* __restrict__ e_in,
            const int* __restrict__ eidx,   // [2][E] int32: dst then src
            const int* __restrict__ perm,   // edge ids sorted by dst
            const ushort* __restrict__ AFh, const ushort* __restrict__ AFl,
            const float* __restrict__ Ab,
            const ushort* __restrict__ Vh, const ushort* __restrict__ Bh,
            const ushort* __restrict__ Ch,
            float* __restrict__ out_h, float* __restrict__ out_e,
            float* __restrict__ e_sum, float* __restrict__ e_sq,
            int E)
{
    __shared__ int eids[TILE], dns[TILE], sns[TILE];
    __shared__ ushort es[TILE * ESP];     // bf16 e_in tile (wave-private spans)
    __shared__ float sbuf[512], qbuf[512];

    const int tid = threadIdx.x;
    const int w = tid >> 6;
    const int l = tid & 63;
    const int l15 = l & 15;
    const int lk = l >> 4;
    const int e0 = blockIdx.x * TILE;

    if (tid < TILE) {
        int e = e0 + tid;
        int ec = e < E ? e : E - 1;
        int eid = perm[ec];
        eids[tid] = eid;
        dns[tid] = eidx[eid];
        sns[tid] = eidx[(size_t)E + eid];
    }
    __syncthreads();

    f32x4 acc[8];
    #pragma unroll
    for (int n = 0; n < 8; ++n) acc[n] = (f32x4){0.f, 0.f, 0.f, 0.f};

    {
        const int arow = w * 16 + l15;
        const float* er = e_in + (size_t)eids[arow] * D;
        f32x4 x0 = __builtin_nontemporal_load(
            reinterpret_cast<const f32x4*>(er + lk * 8));
        f32x4 x1 = __builtin_nontemporal_load(
            reinterpret_cast<const f32x4*>(er + lk * 8 + 4));
        #pragma unroll
        for (int s = 0; s < 4; ++s) {
            // prefetch step s+1 BEFORE this step's convert+MFMA (hides HBM lat)
            f32x4 n0, n1;
            if (s < 3) {
                n0 = __builtin_nontemporal_load(
                    reinterpret_cast<const f32x4*>(er + (s + 1) * 32 + lk * 8));
                n1 = __builtin_nontemporal_load(
                    reinterpret_cast<const f32x4*>(er + (s + 1) * 32 + lk * 8 + 4));
            }
            s16x8 ah, al;
            cvt_hilo(x0, x1, ah, al);
            *reinterpret_cast<s16x8*>(&es[arow * ESP + s * 32 + lk * 8]) = ah;
            #pragma unroll
            for (int t = 0; t < 8; ++t) {
                size_t fo = ((size_t)((s * 8 + t) * 64 + l)) * 8;
                s16x8 bh = *reinterpret_cast<const s16x8*>(AFh + fo);
                s16x8 bl = *reinterpret_cast<const s16x8*>(AFl + fo);
                acc[t] = __builtin_amdgcn_mfma_f32_16x16x32_bf16(ah, bh, acc[t], 0, 0, 0);
                acc[t] = __builtin_amdgcn_mfma_f32_16x16x32_bf16(ah, bl, acc[t], 0, 0, 0);
                acc[t] = __builtin_amdgcn_mfma_f32_16x16x32_bf16(al, bh, acc[t], 0, 0, 0);
                if ((t & 1) == 1 && t < 7) __builtin_amdgcn_sched_barrier(0);
            }
            if (s < 3) { x0 = n0; x1 = n1; }
        }
    }

    // epilogue in frag layout, TWO n-halves; fence only every 2nd row-iter.
    const int mrow0 = w * 16 + lk * 4;
    #pragma unroll
    for (int h = 0; h < 2; ++h) {
        float abv[4], sst[4], sq[4], rs[4];
        #pragma unroll
        for (int n = 0; n < 4; ++n) {
            abv[n] = Ab[(h * 4 + n) * 16 + l15];
            sst[n] = 0.f; sq[n] = 0.f; rs[n] = 0.f;
        }
        #pragma unroll
        for (int r = 0; r < 4; ++r) {
            int row = mrow0 + r;
            int eid = eids[row], dn = dns[row], sn = sns[row];
            bool valid = (e0 + row) < E;
            if (valid) {
                const ushort* br = Bh + (size_t)dn * D;
                const ushort* cr = Ch + (size_t)sn * D;
                float* oe = out_e + (size_t)eid * D;
                #pragma unroll
                for (int n = 0; n < 4; ++n) {
                    int col = (h * 4 + n) * 16 + l15;
                    float pre = acc[h * 4 + n][r] + abv[n]
                              + bf16_to_f32(br[col]) + bf16_to_f32(cr[col]);
                    __builtin_nontemporal_store(pre, oe + col);
                    sst[n] += pre;
                    sq[n] += pre * pre;
                }
            }
            const ushort* vr = Vh + (size_t)sn * D;
            #pragma unroll
            for (int n = 0; n < 4; ++n) {
                int col = (h * 4 + n) * 16 + l15;
                float ein = bf16_to_f32(es[row * ESP + col]);
                float m = valid ? bf16_to_f32(vr[col]) / (1.f + __expf(-ein)) : 0.f;
                rs[n] += m;
            }
            bool flush = (r == 3) || (dns[row + 1] != dn);
            if (flush) {
                float* dst = out_h + (size_t)dn * D;
                #pragma unroll
                for (int n = 0; n < 4; ++n) {
                    unsafeAtomicAdd(dst + (h * 4 + n) * 16 + l15, rs[n]);
                    rs[n] = 0.f;
                }
            }
            if (r & 1) __builtin_amdgcn_sched_barrier(0);
        }
        #pragma unroll
        for (int n = 0; n < 4; ++n) {
            sst[n] += __shfl_xor(sst[n], 16); sst[n] += __shfl_xor(sst[n], 32);
            sq[n]  += __shfl_xor(sq[n], 16);  sq[n]  += __shfl_xor(sq[n], 32);
        }
        if (l < 16) {
            #pragma unroll
            for (int n = 0; n < 4; ++n) {
                sbuf[w * 128 + (h * 4 + n) * 16 + l] = sst[n];
                qbuf[w * 128 + (h * 4 + n) * 16 + l] = sq[n];
            }
        }
    }
    __syncthreads();
    if (tid < 128) {
        float ss = sbuf[tid] + sbuf[128 + tid] + sbuf[256 + tid] + sbuf[384 + tid];
        float qq = qbuf[tid] + qbuf[128 + tid] + qbuf[256 + tid] + qbuf[384 + tid];
        unsafeAtomicAdd(&e_sum[tid], ss);
        unsafeAtomicAdd(&e_sq[tid], qq);
    }
}

// ---------------- col stats over a [rows x 128] matrix (float4) ----------------
__global__ void col_stats_k(const float* __restrict__ X, int rows,
                            float* __restrict__ sum, float* __restrict__ sumsq)
{
    __shared__ float sr[8][128], qr[8][128];
    const int tx = threadIdx.x & 31;
    const int rp = threadIdx.x >> 5;
    float4 s = make_float4(0.f, 0.f, 0.f, 0.f);
    float4 q = make_float4(0.f, 0.f, 0.f, 0.f);
    for (int r = blockIdx.x * 8 + rp; r < rows; r += gridDim.x * 8) {
        float4 v = *reinterpret_cast<const float4*>(X + (size_t)r * D + 4 * tx);
        s.x += v.x; q.x += v.x * v.x;
        s.y += v.y; q.y += v.y * v.y;
        s.z += v.z; q.z += v.z * v.z;
        s.w += v.w; q.w += v.w * v.w;
    }
    *reinterpret_cast<float4*>(&sr[rp][4 * tx]) = s;
    *reinterpret_cast<float4*>(&qr[rp][4 * tx]) = q;
    __syncthreads();
    if (threadIdx.x < 128) {
        float ss = 0.f, qq = 0.f;
        #pragma unroll
        for (int t = 0; t < 8; ++t) { ss += sr[t][threadIdx.x]; qq += qr[t][threadIdx.x]; }
        unsafeAtomicAdd(&sum[threadIdx.x], ss);
        unsafeAtomicAdd(&sumsq[threadIdx.x], qq);
    }
}

// ---------------- finalize: in-place BN + ReLU + residual (float4) ----------------
__global__ void finalize_k(const float* __restrict__ res_in,
                           float* __restrict__ out,
                           const float* __restrict__ sum, const float* __restrict__ sumsq,
                           const float* __restrict__ gamma, const float* __restrict__ beta,
                           float cntInv, int rows)
{
    const int tx = threadIdx.x & 31;
    const int rp = threadIdx.x >> 5;
    const int col4 = 4 * tx;
    float mu[4], g[4], b[4];
    #pragma unroll
    for (int i = 0; i < 4; ++i) {
        float m = sum[col4 + i] * cntInv;
        float var = sumsq[col4 + i] * cntInv - m * m;
        mu[i] = m;
        g[i] = gamma[col4 + i] * rsqrtf(var + 1e-5f);
        b[i] = beta[col4 + i];
    }
    for (int r = blockIdx.x * 8 + rp; r < rows; r += gridDim.x * 8) {
        size_t o = (size_t)r * D + col4;
        float4 x = *reinterpret_cast<const float4*>(out + o);
        float4 rr = *reinterpret_cast<const float4*>(res_in + o);
        float4 y;
        y.x = rr.x + fmaxf(g[0] * (x.x - mu[0]) + b[0], 0.f);
        y.y = rr.y + fmaxf(g[1] * (x.y - mu[1]) + b[1], 0.f);
        y.z = rr.z + fmaxf(g[2] * (x.z - mu[2]) + b[2], 0.f);
        y.w = rr.w + fmaxf(g[3] * (x.w - mu[3]) + b[3], 0.f);
        *reinterpret_cast<float4*>(out + o) = y;
    }
}

extern "C" void kernel_launch(void* const* d_in, const int* in_sizes, int n_in,
                              void* d_out, int out_size, void* d_ws, size_t ws_size,
                              hipStream_t stream)
{
    const float* h_in = (const float*)d_in[0];
    const float* e_in = (const float*)d_in[1];
    const int*   eidx = (const int*)d_in[2];
    const float* Uw = (const float*)d_in[3];  const float* Ub = (const float*)d_in[4];
    const float* Vw = (const float*)d_in[5];  const float* Vb = (const float*)d_in[6];
    const float* Aw = (const float*)d_in[7];  const float* Ab = (const float*)d_in[8];
    const float* Bw = (const float*)d_in[9];  const float* Bb = (const float*)d_in[10];
    const float* Cw = (const float*)d_in[11]; const float* Cb = (const float*)d_in[12];
    const float* hg = (const float*)d_in[13]; const float* hb = (const float*)d_in[14];
    const float* eg = (const float*)d_in[15]; const float* eb = (const float*)d_in[16];

    const int N = in_sizes[0] / D;
    const int E = in_sizes[1] / D;

    float* out_h = (float*)d_out;
    float* out_e = out_h + (size_t)N * D;

    // workspace: bf16 tables first, then stats/sort/frag buffers
    ushort* Vh16 = (ushort*)d_ws;
    ushort* Bh16 = Vh16 + (size_t)N * D;
    ushort* Ch16 = Bh16 + (size_t)N * D;
    float* stats = (float*)(Ch16 + (size_t)N * D);
    float* h_sum = stats;       float* h_sq = stats + 128;
    float* e_sum = stats + 256; float* e_sq = stats + 384;
    int* deg    = (int*)(stats + 512);
    int* off    = deg + N;
    int* cursor = off + N + 1;
    int* perm   = cursor + N;
    ushort* Fh = (ushort*)(perm + E);        // 5*16384 ushort
    ushort* Fl = Fh + 5 * 16384;

    zero_misc_k<<<(N + 255) / 256, 256, 0, stream>>>(stats, deg, N);
    wconv5_k<<<(5 * 16384 + 255) / 256, 256, 0, stream>>>(Uw, Vw, Bw, Cw, Aw, Fh, Fl);
    hist_k<<<1024, 256, 0, stream>>>(eidx, deg, E);
    scan_k<<<1, 1024, 0, stream>>>(deg, off, cursor, N);
    scatter_k<<<1024, 256, 0, stream>>>(eidx, cursor, perm, E);
    node_linear_k<<<(N + TILE - 1) / TILE, 256, 0, stream>>>(
        h_in, Fh, Fl, Ub, Vb, Bb, Cb, out_h, Vh16, Bh16, Ch16, N);
    edge_k<<<(E + TILE - 1) / TILE, 256, 0, stream>>>(
        e_in, eidx, perm, Fh + 4 * 16384, Fl + 4 * 16384, Ab, Vh16, Bh16, Ch16,
        out_h, out_e, e_sum, e_sq, E);
    col_stats_k<<<256, 256, 0, stream>>>(out_h, N, h_sum, h_sq);
    finalize_k<<<256, 256, 0, stream>>>(h_in, out_h, h_sum, h_sq, hg, hb, 1.0f / (float)N, N);
    finalize_k<<<2048, 256, 0, stream>>>(e_in, out_e, e_sum, e_sq, eg, eb, 1.0f / (float)E, E);
}

// Round 22
// 856.742 us; speedup vs baseline: 1.0431x; 1.0102x over previous
//
#include <hip/hip_runtime.h>
#include <hip/hip_bf16.h>
#include <math.h>

#define D 128
#define TILE 64
#define ESP 136   // es row stride (ushorts)

typedef __attribute__((ext_vector_type(8))) short s16x8;  // 8 bf16 (4 VGPRs)
typedef __attribute__((ext_vector_type(4))) float f32x4;  // MFMA accumulator

__device__ inline ushort f2bf(float x) {   // RNE via v_cvt
    __hip_bfloat16 h = __float2bfloat16(x);
    return *reinterpret_cast<ushort*>(&h);
}
__device__ inline float bf16_to_f32(ushort h) {
    return __uint_as_float(((unsigned)h) << 16);
}

// convert 8 floats -> hi/lo bf16 frags
__device__ inline void cvt_hilo(f32x4 x0, f32x4 x1, s16x8& ah, s16x8& al) {
    #pragma unroll
    for (int j = 0; j < 4; ++j) {
        ushort hb = f2bf(x0[j]);
        ah[j] = (short)hb;
        al[j] = (short)f2bf(x0[j] - bf16_to_f32(hb));
        ushort hb2 = f2bf(x1[j]);
        ah[j + 4] = (short)hb2;
        al[j + 4] = (short)f2bf(x1[j] - bf16_to_f32(hb2));
    }
}

// ---------------- zero stats (512 f) + degree (N ints) ----------------
__global__ void zero_misc_k(float* stats, int* deg, int n) {
    int i = blockIdx.x * blockDim.x + threadIdx.x;
    if (i < 512) stats[i] = 0.f;
    if (i < n) deg[i] = 0;
}

// ---------------- weight prep: pack 5 weights into MFMA B-frag layout ----------------
__global__ void wconv5_k(const float* __restrict__ W0, const float* __restrict__ W1,
                         const float* __restrict__ W2, const float* __restrict__ W3,
                         const float* __restrict__ W4,
                         ushort* __restrict__ Fh, ushort* __restrict__ Fl) {
    int i = blockIdx.x * blockDim.x + threadIdx.x;
    if (i >= 5 * 16384) return;
    int wsel = i >> 14;
    int rem = i & 16383;
    int j = rem & 7;
    int l = (rem >> 3) & 63;
    int st = rem >> 9;             // s*8 + t
    int s = st >> 3, t = st & 7;
    int l15 = l & 15, lk = l >> 4;
    const float* W = wsel == 0 ? W0 : wsel == 1 ? W1 : wsel == 2 ? W2 : wsel == 3 ? W3 : W4;
    float x = W[(size_t)(t * 16 + l15) * D + s * 32 + lk * 8 + j];
    ushort h = f2bf(x);
    Fh[i] = h;
    Fl[i] = f2bf(x - bf16_to_f32(h));
}

// ---------------- K1: fused node linear via split-bf16 MFMA ----------------
// outU (out_h seed) stays f32 NATURAL layout. V/B/C tables are bf16 in
// PERMUTED layout: table[node][l15*8 + n] holds col n*16+l15 — so the edge
// kernel's per-lane gather is ONE contiguous s16x8 instead of 8 scalars.
__global__ __launch_bounds__(256, 4)
void node_linear_k(const float* __restrict__ h_in,
                   const ushort* __restrict__ Fh, const ushort* __restrict__ Fl,
                   const float* __restrict__ Ub, const float* __restrict__ Vb,
                   const float* __restrict__ Bb, const float* __restrict__ Cb,
                   float* __restrict__ outU, ushort* __restrict__ outV,
                   ushort* __restrict__ outB, ushort* __restrict__ outC,
                   int M)
{
    const int tid = threadIdx.x;
    const int w = tid >> 6, l = tid & 63;
    const int l15 = l & 15, lk = l >> 4;
    const int row0 = blockIdx.x * TILE;

    s16x8 ahs[4], als[4];
    {
        int arow = row0 + w * 16 + l15;
        if (arow >= M) arow = M - 1;
        const float* hr = h_in + (size_t)arow * D;
        #pragma unroll
        for (int s = 0; s < 4; ++s) {
            f32x4 x0 = *reinterpret_cast<const f32x4*>(hr + s * 32 + lk * 8);
            f32x4 x1 = *reinterpret_cast<const f32x4*>(hr + s * 32 + lk * 8 + 4);
            cvt_hilo(x0, x1, ahs[s], als[s]);
        }
    }

    const int mrow0 = row0 + w * 16 + lk * 4;

    #pragma unroll
    for (int wsel = 0; wsel < 4; ++wsel) {
        f32x4 acc[8];
        #pragma unroll
        for (int n = 0; n < 8; ++n) acc[n] = (f32x4){0.f, 0.f, 0.f, 0.f};

        #pragma unroll
        for (int s = 0; s < 4; ++s) {
            #pragma unroll
            for (int t = 0; t < 8; ++t) {
                size_t fo = ((size_t)((wsel * 32 + s * 8 + t) * 64 + l)) * 8;
                s16x8 bh = *reinterpret_cast<const s16x8*>(Fh + fo);
                s16x8 bl = *reinterpret_cast<const s16x8*>(Fl + fo);
                acc[t] = __builtin_amdgcn_mfma_f32_16x16x32_bf16(ahs[s], bh, acc[t], 0, 0, 0);
                acc[t] = __builtin_amdgcn_mfma_f32_16x16x32_bf16(ahs[s], bl, acc[t], 0, 0, 0);
                acc[t] = __builtin_amdgcn_mfma_f32_16x16x32_bf16(als[s], bh, acc[t], 0, 0, 0);
                if ((t & 1) == 1 && t < 7) __builtin_amdgcn_sched_barrier(0);
            }
        }

        const float* bias = wsel == 0 ? Ub : wsel == 1 ? Vb : wsel == 2 ? Bb : Cb;
        float bv[8];
        #pragma unroll
        for (int n = 0; n < 8; ++n) bv[n] = bias[n * 16 + l15];
        #pragma unroll
        for (int r = 0; r < 4; ++r) {
            int row = mrow0 + r;
            if (row < M) {
                if (wsel == 0) {
                    float* orow = outU + (size_t)row * D;
                    #pragma unroll
                    for (int n = 0; n < 8; ++n)
                        orow[n * 16 + l15] = acc[n][r] + bv[n];
                } else {
                    ushort* orow = (wsel == 1 ? outV : wsel == 2 ? outB : outC) + (size_t)row * D;
                    s16x8 pk;
                    #pragma unroll
                    for (int n = 0; n < 8; ++n)
                        pk[n] = (short)f2bf(acc[n][r] + bv[n]);
                    *reinterpret_cast<s16x8*>(orow + l15 * 8) = pk;   // permuted row
                }
            }
        }
    }
}

// ---------------- counting sort: histogram / scan / scatter ----------------
__global__ void hist_k(const int* __restrict__ dst, int* __restrict__ deg, int E) {
    for (int e = blockIdx.x * blockDim.x + threadIdx.x; e < E; e += gridDim.x * blockDim.x)
        atomicAdd(&deg[dst[e]], 1);
}

__global__ void scan_k(const int* __restrict__ deg, int* __restrict__ off,
                       int* __restrict__ cursor, int n)
{
    __shared__ int wsum[16], wpre[16];
    const int tid = threadIdx.x, lane = tid & 63, w = tid >> 6;
    int carry = 0;  // live only in thread 0
    for (int base = 0; base < n; base += 1024) {
        int i = base + tid;
        int v = (i < n) ? deg[i] : 0;
        int x = v;
        #pragma unroll
        for (int d = 1; d < 64; d <<= 1) {
            int t = __shfl_up(x, d);
            if (lane >= d) x += t;
        }
        if (lane == 63) wsum[w] = x;
        __syncthreads();
        if (tid == 0) {
            int run = carry;
            #pragma unroll
            for (int j = 0; j < 16; ++j) { int t = wsum[j]; wpre[j] = run; run += t; }
            carry = run;
        }
        __syncthreads();
        int excl = wpre[w] + x - v;
        if (i < n) { off[i] = excl; cursor[i] = excl; }
    }
    if (tid == 0) off[n] = carry;
}

__global__ void scatter_k(const int* __restrict__ dst, int* __restrict__ cursor,
                          int* __restrict__ perm, int E)
{
    for (int e = blockIdx.x * blockDim.x + threadIdx.x; e < E; e += gridDim.x * blockDim.x) {
        int pos = atomicAdd(&cursor[dst[e]], 1);
        perm[pos] = e;
    }
}

// ---------------- K2: edge kernel, split-bf16 MFMA, vectorized epilogue ----------------
// Permuted bf16 tables: per (row, table) gather = ONE s16x8. pre stored
// PERMUTED (out_pre[edge][l15*8+n], f32) via two float4 nt-stores; finalize
// un-permutes. Epilogue vmem instr: ~128 -> ~20 per thread.
__global__ __launch_bounds__(256, 5)
void edge_k(const float* __restrict__ e_in,
            const int* __restrict__ eidx,   // [2][E] int32: dst then src
            const int* __restrict__ perm,   // edge ids sorted by dst
            const ushort* __restrict__ AFh, const ushort* __restrict__ AFl,
            const float* __restrict__ Ab,
            const ushort* __restrict__ Vh, const ushort* __restrict__ Bh,
            const ushort* __restrict__ Ch,
            float* __restrict__ out_h, float* __restrict__ out_pre,
            float* __restrict__ e_sum, float* __restrict__ e_sq,
            int E)
{
    __shared__ int eids[TILE], dns[TILE], sns[TILE];
    __shared__ ushort es[TILE * ESP];     // bf16 e_in tile (wave-private spans)
    __shared__ float sbuf[512], qbuf[512];

    const int tid = threadIdx.x;
    const int w = tid >> 6;
    const int l = tid & 63;
    const int l15 = l & 15;
    const int lk = l >> 4;
    const int e0 = blockIdx.x * TILE;

    if (tid < TILE) {
        int e = e0 + tid;
        int ec = e < E ? e : E - 1;
        int eid = perm[ec];
        eids[tid] = eid;
        dns[tid] = eidx[eid];
        sns[tid] = eidx[(size_t)E + eid];
    }
    __syncthreads();

    f32x4 acc[8];
    #pragma unroll
    for (int n = 0; n < 8; ++n) acc[n] = (f32x4){0.f, 0.f, 0.f, 0.f};

    {
        const int arow = w * 16 + l15;
        const float* er = e_in + (size_t)eids[arow] * D;
        f32x4 x0 = __builtin_nontemporal_load(
            reinterpret_cast<const f32x4*>(er + lk * 8));
        f32x4 x1 = __builtin_nontemporal_load(
            reinterpret_cast<const f32x4*>(er + lk * 8 + 4));
        #pragma unroll
        for (int s = 0; s < 4; ++s) {
            f32x4 n0, n1;
            if (s < 3) {
                n0 = __builtin_nontemporal_load(
                    reinterpret_cast<const f32x4*>(er + (s + 1) * 32 + lk * 8));
                n1 = __builtin_nontemporal_load(
                    reinterpret_cast<const f32x4*>(er + (s + 1) * 32 + lk * 8 + 4));
            }
            s16x8 ah, al;
            cvt_hilo(x0, x1, ah, al);
            *reinterpret_cast<s16x8*>(&es[arow * ESP + s * 32 + lk * 8]) = ah;
            #pragma unroll
            for (int t = 0; t < 8; ++t) {
                size_t fo = ((size_t)((s * 8 + t) * 64 + l)) * 8;
                s16x8 bh = *reinterpret_cast<const s16x8*>(AFh + fo);
                s16x8 bl = *reinterpret_cast<const s16x8*>(AFl + fo);
                acc[t] = __builtin_amdgcn_mfma_f32_16x16x32_bf16(ah, bh, acc[t], 0, 0, 0);
                acc[t] = __builtin_amdgcn_mfma_f32_16x16x32_bf16(ah, bl, acc[t], 0, 0, 0);
                acc[t] = __builtin_amdgcn_mfma_f32_16x16x32_bf16(al, bh, acc[t], 0, 0, 0);
                if ((t & 1) == 1 && t < 7) __builtin_amdgcn_sched_barrier(0);
            }
            if (s < 3) { x0 = n0; x1 = n1; }
        }
    }

    // epilogue: single n=0..8 loop; per row-iter 3 vector gathers + 2 stores
    float abv[8];
    #pragma unroll
    for (int n = 0; n < 8; ++n) abv[n] = Ab[n * 16 + l15];

    float sst[8], sq[8], rs[8];
    #pragma unroll
    for (int n = 0; n < 8; ++n) { sst[n] = 0.f; sq[n] = 0.f; rs[n] = 0.f; }

    const int mrow0 = w * 16 + lk * 4;
    #pragma unroll
    for (int r = 0; r < 4; ++r) {
        int row = mrow0 + r;
        int eid = eids[row], dn = dns[row], sn = sns[row];
        bool valid = (e0 + row) < E;
        s16x8 br8 = *reinterpret_cast<const s16x8*>(Bh + (size_t)dn * D + l15 * 8);
        s16x8 cr8 = *reinterpret_cast<const s16x8*>(Ch + (size_t)sn * D + l15 * 8);
        s16x8 vr8 = *reinterpret_cast<const s16x8*>(Vh + (size_t)sn * D + l15 * 8);
        if (valid) {
            f32x4 p0, p1;
            #pragma unroll
            for (int n = 0; n < 4; ++n) {
                p0[n] = acc[n][r] + abv[n]
                      + bf16_to_f32((ushort)br8[n]) + bf16_to_f32((ushort)cr8[n]);
                p1[n] = acc[n + 4][r] + abv[n + 4]
                      + bf16_to_f32((ushort)br8[n + 4]) + bf16_to_f32((ushort)cr8[n + 4]);
            }
            float* op = out_pre + (size_t)eid * D + l15 * 8;
            __builtin_nontemporal_store(p0, reinterpret_cast<f32x4*>(op));
            __builtin_nontemporal_store(p1, reinterpret_cast<f32x4*>(op + 4));
            #pragma unroll
            for (int n = 0; n < 4; ++n) {
                sst[n] += p0[n];     sq[n] += p0[n] * p0[n];
                sst[n + 4] += p1[n]; sq[n + 4] += p1[n] * p1[n];
            }
        }
        #pragma unroll
        for (int n = 0; n < 8; ++n) {
            float ein = bf16_to_f32(es[row * ESP + n * 16 + l15]);
            float m = valid ? bf16_to_f32((ushort)vr8[n]) / (1.f + __expf(-ein)) : 0.f;
            rs[n] += m;
        }
        bool flush = (r == 3) || (dns[row + 1] != dn);
        if (flush) {
            float* dst = out_h + (size_t)dn * D;
            #pragma unroll
            for (int n = 0; n < 8; ++n) {
                unsafeAtomicAdd(dst + n * 16 + l15, rs[n]);
                rs[n] = 0.f;
            }
        }
        if (r & 1) __builtin_amdgcn_sched_barrier(0);
    }

    // stats: lanes l, l^16, l^32, l^48 share the same col set -> shfl reduce
    #pragma unroll
    for (int n = 0; n < 8; ++n) {
        sst[n] += __shfl_xor(sst[n], 16); sst[n] += __shfl_xor(sst[n], 32);
        sq[n]  += __shfl_xor(sq[n], 16);  sq[n]  += __shfl_xor(sq[n], 32);
    }
    if (l < 16) {
        #pragma unroll
        for (int n = 0; n < 8; ++n) {
            sbuf[w * 128 + n * 16 + l] = sst[n];
            qbuf[w * 128 + n * 16 + l] = sq[n];
        }
    }
    __syncthreads();
    if (tid < 128) {
        float ss = sbuf[tid] + sbuf[128 + tid] + sbuf[256 + tid] + sbuf[384 + tid];
        float qq = qbuf[tid] + qbuf[128 + tid] + qbuf[256 + tid] + qbuf[384 + tid];
        unsafeAtomicAdd(&e_sum[tid], ss);
        unsafeAtomicAdd(&e_sq[tid], qq);
    }
}

// ---------------- col stats over a [rows x 128] matrix (float4) ----------------
__global__ void col_stats_k(const float* __restrict__ X, int rows,
                            float* __restrict__ sum, float* __restrict__ sumsq)
{
    __shared__ float sr[8][128], qr[8][128];
    const int tx = threadIdx.x & 31;
    const int rp = threadIdx.x >> 5;
    float4 s = make_float4(0.f, 0.f, 0.f, 0.f);
    float4 q = make_float4(0.f, 0.f, 0.f, 0.f);
    for (int r = blockIdx.x * 8 + rp; r < rows; r += gridDim.x * 8) {
        float4 v = *reinterpret_cast<const float4*>(X + (size_t)r * D + 4 * tx);
        s.x += v.x; q.x += v.x * v.x;
        s.y += v.y; q.y += v.y * v.y;
        s.z += v.z; q.z += v.z * v.z;
        s.w += v.w; q.w += v.w * v.w;
    }
    *reinterpret_cast<float4*>(&sr[rp][4 * tx]) = s;
    *reinterpret_cast<float4*>(&qr[rp][4 * tx]) = q;
    __syncthreads();
    if (threadIdx.x < 128) {
        float ss = 0.f, qq = 0.f;
        #pragma unroll
        for (int t = 0; t < 8; ++t) { ss += sr[t][threadIdx.x]; qq += qr[t][threadIdx.x]; }
        unsafeAtomicAdd(&sum[threadIdx.x], ss);
        unsafeAtomicAdd(&sumsq[threadIdx.x], qq);
    }
}

// ---------------- finalize (natural layout, h-side) ----------------
__global__ void finalize_k(const float* __restrict__ res_in,
                           float* __restrict__ out,
                           const float* __restrict__ sum, const float* __restrict__ sumsq,
                           const float* __restrict__ gamma, const float* __restrict__ beta,
                           float cntInv, int rows)
{
    const int tx = threadIdx.x & 31;
    const int rp = threadIdx.x >> 5;
    const int col4 = 4 * tx;
    float mu[4], g[4], b[4];
    #pragma unroll
    for (int i = 0; i < 4; ++i) {
        float m = sum[col4 + i] * cntInv;
        float var = sumsq[col4 + i] * cntInv - m * m;
        mu[i] = m;
        g[i] = gamma[col4 + i] * rsqrtf(var + 1e-5f);
        b[i] = beta[col4 + i];
    }
    for (int r = blockIdx.x * 8 + rp; r < rows; r += gridDim.x * 8) {
        size_t o = (size_t)r * D + col4;
        float4 x = *reinterpret_cast<const float4*>(out + o);
        float4 rr = *reinterpret_cast<const float4*>(res_in + o);
        float4 y;
        y.x = rr.x + fmaxf(g[0] * (x.x - mu[0]) + b[0], 0.f);
        y.y = rr.y + fmaxf(g[1] * (x.y - mu[1]) + b[1], 0.f);
        y.z = rr.z + fmaxf(g[2] * (x.z - mu[2]) + b[2], 0.f);
        y.w = rr.w + fmaxf(g[3] * (x.w - mu[3]) + b[3], 0.f);
        *reinterpret_cast<float4*>(out + o) = y;
    }
}

// ---------------- finalize for PERMUTED pre (e-side, in-place) ----------------
// out holds permuted pre[row][(j&15)*8 + (j>>4)]; rewrites natural layout.
// Safe in place: each row is handled by 32 lanes of one wave (lockstep reads
// complete before stores issue).
__global__ void finalize_perm_k(const float* __restrict__ res_in,
                                float* out,
                                const float* __restrict__ sum, const float* __restrict__ sumsq,
                                const float* __restrict__ gamma, const float* __restrict__ beta,
                                float cntInv, int rows)
{
    const int tx = threadIdx.x & 31;
    const int rp = threadIdx.x >> 5;
    const int col4 = 4 * tx;
    float mu[4], g[4], b[4];
    #pragma unroll
    for (int i = 0; i < 4; ++i) {
        float m = sum[col4 + i] * cntInv;
        float var = sumsq[col4 + i] * cntInv - m * m;
        mu[i] = m;
        g[i] = gamma[col4 + i] * rsqrtf(var + 1e-5f);
        b[i] = beta[col4 + i];
    }
    for (int r = blockIdx.x * 8 + rp; r < rows; r += gridDim.x * 8) {
        size_t base = (size_t)r * D;
        float x[4];
        #pragma unroll
        for (int i = 0; i < 4; ++i) {
            int j = col4 + i;
            x[i] = out[base + (j & 15) * 8 + (j >> 4)];
        }
        float4 rr = *reinterpret_cast<const float4*>(res_in + base + col4);
        float4 y;
        y.x = rr.x + fmaxf(g[0] * (x[0] - mu[0]) + b[0], 0.f);
        y.y = rr.y + fmaxf(g[1] * (x[1] - mu[1]) + b[1], 0.f);
        y.z = rr.z + fmaxf(g[2] * (x[2] - mu[2]) + b[2], 0.f);
        y.w = rr.w + fmaxf(g[3] * (x[3] - mu[3]) + b[3], 0.f);
        *reinterpret_cast<float4*>(out + base + col4) = y;
    }
}

extern "C" void kernel_launch(void* const* d_in, const int* in_sizes, int n_in,
                              void* d_out, int out_size, void* d_ws, size_t ws_size,
                              hipStream_t stream)
{
    const float* h_in = (const float*)d_in[0];
    const float* e_in = (const float*)d_in[1];
    const int*   eidx = (const int*)d_in[2];
    const float* Uw = (const float*)d_in[3];  const float* Ub = (const float*)d_in[4];
    const float* Vw = (const float*)d_in[5];  const float* Vb = (const float*)d_in[6];
    const float* Aw = (const float*)d_in[7];  const float* Ab = (const float*)d_in[8];
    const float* Bw = (const float*)d_in[9];  const float* Bb = (const float*)d_in[10];
    const float* Cw = (const float*)d_in[11]; const float* Cb = (const float*)d_in[12];
    const float* hg = (const float*)d_in[13]; const float* hb = (const float*)d_in[14];
    const float* eg = (const float*)d_in[15]; const float* eb = (const float*)d_in[16];

    const int N = in_sizes[0] / D;
    const int E = in_sizes[1] / D;

    float* out_h = (float*)d_out;
    float* out_e = out_h + (size_t)N * D;   // holds permuted pre, then final

    ushort* Vh16 = (ushort*)d_ws;
    ushort* Bh16 = Vh16 + (size_t)N * D;
    ushort* Ch16 = Bh16 + (size_t)N * D;
    float* stats = (float*)(Ch16 + (size_t)N * D);
    float* h_sum = stats;       float* h_sq = stats + 128;
    float* e_sum = stats + 256; float* e_sq = stats + 384;
    int* deg    = (int*)(stats + 512);
    int* off    = deg + N;
    int* cursor = off + N + 1;
    int* perm   = cursor + N;
    ushort* Fh = (ushort*)(perm + E);        // 5*16384 ushort
    ushort* Fl = Fh + 5 * 16384;

    zero_misc_k<<<(N + 255) / 256, 256, 0, stream>>>(stats, deg, N);
    wconv5_k<<<(5 * 16384 + 255) / 256, 256, 0, stream>>>(Uw, Vw, Bw, Cw, Aw, Fh, Fl);
    hist_k<<<1024, 256, 0, stream>>>(eidx, deg, E);
    scan_k<<<1, 1024, 0, stream>>>(deg, off, cursor, N);
    scatter_k<<<1024, 256, 0, stream>>>(eidx, cursor, perm, E);
    node_linear_k<<<(N + TILE - 1) / TILE, 256, 0, stream>>>(
        h_in, Fh, Fl, Ub, Vb, Bb, Cb, out_h, Vh16, Bh16, Ch16, N);
    edge_k<<<(E + TILE - 1) / TILE, 256, 0, stream>>>(
        e_in, eidx, perm, Fh + 4 * 16384, Fl + 4 * 16384, Ab, Vh16, Bh16, Ch16,
        out_h, out_e, e_sum, e_sq, E);
    col_stats_k<<<256, 256, 0, stream>>>(out_h, N, h_sum, h_sq);
    finalize_k<<<256, 256, 0, stream>>>(h_in, out_h, h_sum, h_sq, hg, hb, 1.0f / (float)N, N);
    finalize_perm_k<<<2048, 256, 0, stream>>>(e_in, out_e, e_sum, e_sq, eg, eb, 1.0f / (float)E, E);
}

// Round 23
// 832.187 us; speedup vs baseline: 1.0739x; 1.0295x over previous
//
#include <hip/hip_runtime.h>
#include <hip/hip_bf16.h>
#include <math.h>

#define D 128
#define TILE 64
#define ESP 136   // es row stride (ushorts)

typedef __attribute__((ext_vector_type(8))) short s16x8;  // 8 bf16 (4 VGPRs)
typedef __attribute__((ext_vector_type(4))) float f32x4;  // MFMA accumulator

__device__ inline ushort f2bf(float x) {   // RNE via v_cvt
    __hip_bfloat16 h = __float2bfloat16(x);
    return *reinterpret_cast<ushort*>(&h);
}
__device__ inline float bf16_to_f32(ushort h) {
    return __uint_as_float(((unsigned)h) << 16);
}

// convert 8 floats -> hi/lo bf16 frags
__device__ inline void cvt_hilo(f32x4 x0, f32x4 x1, s16x8& ah, s16x8& al) {
    #pragma unroll
    for (int j = 0; j < 4; ++j) {
        ushort hb = f2bf(x0[j]);
        ah[j] = (short)hb;
        al[j] = (short)f2bf(x0[j] - bf16_to_f32(hb));
        ushort hb2 = f2bf(x1[j]);
        ah[j + 4] = (short)hb2;
        al[j + 4] = (short)f2bf(x1[j] - bf16_to_f32(hb2));
    }
}

// ---------------- zero stats (512 f) + degree (N ints) ----------------
__global__ void zero_misc_k(float* stats, int* deg, int n) {
    int i = blockIdx.x * blockDim.x + threadIdx.x;
    if (i < 512) stats[i] = 0.f;
    if (i < n) deg[i] = 0;
}

// ---------------- weight prep: pack 5 weights into MFMA B-frag layout ----------------
__global__ void wconv5_k(const float* __restrict__ W0, const float* __restrict__ W1,
                         const float* __restrict__ W2, const float* __restrict__ W3,
                         const float* __restrict__ W4,
                         ushort* __restrict__ Fh, ushort* __restrict__ Fl) {
    int i = blockIdx.x * blockDim.x + threadIdx.x;
    if (i >= 5 * 16384) return;
    int wsel = i >> 14;
    int rem = i & 16383;
    int j = rem & 7;
    int l = (rem >> 3) & 63;
    int st = rem >> 9;             // s*8 + t
    int s = st >> 3, t = st & 7;
    int l15 = l & 15, lk = l >> 4;
    const float* W = wsel == 0 ? W0 : wsel == 1 ? W1 : wsel == 2 ? W2 : wsel == 3 ? W3 : W4;
    float x = W[(size_t)(t * 16 + l15) * D + s * 32 + lk * 8 + j];
    ushort h = f2bf(x);
    Fh[i] = h;
    Fl[i] = f2bf(x - bf16_to_f32(h));
}

// ---------------- K1: fused node linear via split-bf16 MFMA ----------------
// outU (out_h seed) stays f32 NATURAL layout. V/B/C tables are bf16 in
// PERMUTED layout: table[node][l15*8 + n] holds col n*16+l15.
__global__ __launch_bounds__(256, 4)
void node_linear_k(const float* __restrict__ h_in,
                   const ushort* __restrict__ Fh, const ushort* __restrict__ Fl,
                   const float* __restrict__ Ub, const float* __restrict__ Vb,
                   const float* __restrict__ Bb, const float* __restrict__ Cb,
                   float* __restrict__ outU, ushort* __restrict__ outV,
                   ushort* __restrict__ outB, ushort* __restrict__ outC,
                   int M)
{
    const int tid = threadIdx.x;
    const int w = tid >> 6, l = tid & 63;
    const int l15 = l & 15, lk = l >> 4;
    const int row0 = blockIdx.x * TILE;

    s16x8 ahs[4], als[4];
    {
        int arow = row0 + w * 16 + l15;
        if (arow >= M) arow = M - 1;
        const float* hr = h_in + (size_t)arow * D;
        #pragma unroll
        for (int s = 0; s < 4; ++s) {
            f32x4 x0 = *reinterpret_cast<const f32x4*>(hr + s * 32 + lk * 8);
            f32x4 x1 = *reinterpret_cast<const f32x4*>(hr + s * 32 + lk * 8 + 4);
            cvt_hilo(x0, x1, ahs[s], als[s]);
        }
    }

    const int mrow0 = row0 + w * 16 + lk * 4;

    #pragma unroll
    for (int wsel = 0; wsel < 4; ++wsel) {
        f32x4 acc[8];
        #pragma unroll
        for (int n = 0; n < 8; ++n) acc[n] = (f32x4){0.f, 0.f, 0.f, 0.f};

        #pragma unroll
        for (int s = 0; s < 4; ++s) {
            #pragma unroll
            for (int t = 0; t < 8; ++t) {
                size_t fo = ((size_t)((wsel * 32 + s * 8 + t) * 64 + l)) * 8;
                s16x8 bh = *reinterpret_cast<const s16x8*>(Fh + fo);
                s16x8 bl = *reinterpret_cast<const s16x8*>(Fl + fo);
                acc[t] = __builtin_amdgcn_mfma_f32_16x16x32_bf16(ahs[s], bh, acc[t], 0, 0, 0);
                acc[t] = __builtin_amdgcn_mfma_f32_16x16x32_bf16(ahs[s], bl, acc[t], 0, 0, 0);
                acc[t] = __builtin_amdgcn_mfma_f32_16x16x32_bf16(als[s], bh, acc[t], 0, 0, 0);
                if ((t & 1) == 1 && t < 7) __builtin_amdgcn_sched_barrier(0);
            }
        }

        const float* bias = wsel == 0 ? Ub : wsel == 1 ? Vb : wsel == 2 ? Bb : Cb;
        float bv[8];
        #pragma unroll
        for (int n = 0; n < 8; ++n) bv[n] = bias[n * 16 + l15];
        #pragma unroll
        for (int r = 0; r < 4; ++r) {
            int row = mrow0 + r;
            if (row < M) {
                if (wsel == 0) {
                    float* orow = outU + (size_t)row * D;
                    #pragma unroll
                    for (int n = 0; n < 8; ++n)
                        orow[n * 16 + l15] = acc[n][r] + bv[n];
                } else {
                    ushort* orow = (wsel == 1 ? outV : wsel == 2 ? outB : outC) + (size_t)row * D;
                    s16x8 pk;
                    #pragma unroll
                    for (int n = 0; n < 8; ++n)
                        pk[n] = (short)f2bf(acc[n][r] + bv[n]);
                    *reinterpret_cast<s16x8*>(orow + l15 * 8) = pk;   // permuted row
                }
            }
        }
    }
}

// ---------------- counting sort: histogram / scan / scatter ----------------
__global__ void hist_k(const int* __restrict__ dst, int* __restrict__ deg, int E) {
    for (int e = blockIdx.x * blockDim.x + threadIdx.x; e < E; e += gridDim.x * blockDim.x)
        atomicAdd(&deg[dst[e]], 1);
}

__global__ void scan_k(const int* __restrict__ deg, int* __restrict__ off,
                       int* __restrict__ cursor, int n)
{
    __shared__ int wsum[16], wpre[16];
    const int tid = threadIdx.x, lane = tid & 63, w = tid >> 6;
    int carry = 0;  // live only in thread 0
    for (int base = 0; base < n; base += 1024) {
        int i = base + tid;
        int v = (i < n) ? deg[i] : 0;
        int x = v;
        #pragma unroll
        for (int d = 1; d < 64; d <<= 1) {
            int t = __shfl_up(x, d);
            if (lane >= d) x += t;
        }
        if (lane == 63) wsum[w] = x;
        __syncthreads();
        if (tid == 0) {
            int run = carry;
            #pragma unroll
            for (int j = 0; j < 16; ++j) { int t = wsum[j]; wpre[j] = run; run += t; }
            carry = run;
        }
        __syncthreads();
        int excl = wpre[w] + x - v;
        if (i < n) { off[i] = excl; cursor[i] = excl; }
    }
    if (tid == 0) off[n] = carry;
}

__global__ void scatter_k(const int* __restrict__ dst, int* __restrict__ cursor,
                          int* __restrict__ perm, int E)
{
    for (int e = blockIdx.x * blockDim.x + threadIdx.x; e < E; e += gridDim.x * blockDim.x) {
        int pos = atomicAdd(&cursor[dst[e]], 1);
        perm[pos] = e;
    }
}

// ---------------- K2: edge kernel, split-bf16 MFMA, vectorized epilogue ----------------
// 4 waves/SIMD (cap 128) + NO epilogue fences: all 12 vector gathers of the
// epilogue overlap -> ~48 outstanding/SIMD (was ~30), attacking the 2.0 TB/s
// latency wall head-on.
__global__ __launch_bounds__(256, 4)
void edge_k(const float* __restrict__ e_in,
            const int* __restrict__ eidx,   // [2][E] int32: dst then src
            const int* __restrict__ perm,   // edge ids sorted by dst
            const ushort* __restrict__ AFh, const ushort* __restrict__ AFl,
            const float* __restrict__ Ab,
            const ushort* __restrict__ Vh, const ushort* __restrict__ Bh,
            const ushort* __restrict__ Ch,
            float* __restrict__ out_h, float* __restrict__ out_pre,
            float* __restrict__ e_sum, float* __restrict__ e_sq,
            int E)
{
    __shared__ int eids[TILE], dns[TILE], sns[TILE];
    __shared__ ushort es[TILE * ESP];     // bf16 e_in tile (wave-private spans)
    __shared__ float sbuf[512], qbuf[512];

    const int tid = threadIdx.x;
    const int w = tid >> 6;
    const int l = tid & 63;
    const int l15 = l & 15;
    const int lk = l >> 4;
    const int e0 = blockIdx.x * TILE;

    if (tid < TILE) {
        int e = e0 + tid;
        int ec = e < E ? e : E - 1;
        int eid = perm[ec];
        eids[tid] = eid;
        dns[tid] = eidx[eid];
        sns[tid] = eidx[(size_t)E + eid];
    }
    __syncthreads();

    f32x4 acc[8];
    #pragma unroll
    for (int n = 0; n < 8; ++n) acc[n] = (f32x4){0.f, 0.f, 0.f, 0.f};

    {
        const int arow = w * 16 + l15;
        const float* er = e_in + (size_t)eids[arow] * D;
        f32x4 x0 = __builtin_nontemporal_load(
            reinterpret_cast<const f32x4*>(er + lk * 8));
        f32x4 x1 = __builtin_nontemporal_load(
            reinterpret_cast<const f32x4*>(er + lk * 8 + 4));
        #pragma unroll
        for (int s = 0; s < 4; ++s) {
            f32x4 n0, n1;
            if (s < 3) {
                n0 = __builtin_nontemporal_load(
                    reinterpret_cast<const f32x4*>(er + (s + 1) * 32 + lk * 8));
                n1 = __builtin_nontemporal_load(
                    reinterpret_cast<const f32x4*>(er + (s + 1) * 32 + lk * 8 + 4));
            }
            s16x8 ah, al;
            cvt_hilo(x0, x1, ah, al);
            *reinterpret_cast<s16x8*>(&es[arow * ESP + s * 32 + lk * 8]) = ah;
            #pragma unroll
            for (int t = 0; t < 8; ++t) {
                size_t fo = ((size_t)((s * 8 + t) * 64 + l)) * 8;
                s16x8 bh = *reinterpret_cast<const s16x8*>(AFh + fo);
                s16x8 bl = *reinterpret_cast<const s16x8*>(AFl + fo);
                acc[t] = __builtin_amdgcn_mfma_f32_16x16x32_bf16(ah, bh, acc[t], 0, 0, 0);
                acc[t] = __builtin_amdgcn_mfma_f32_16x16x32_bf16(ah, bl, acc[t], 0, 0, 0);
                acc[t] = __builtin_amdgcn_mfma_f32_16x16x32_bf16(al, bh, acc[t], 0, 0, 0);
                if ((t & 1) == 1 && t < 7) __builtin_amdgcn_sched_barrier(0);
            }
            if (s < 3) { x0 = n0; x1 = n1; }
        }
    }

    // epilogue: single n=0..8 loop; NO fences -> all row-iters' gathers overlap
    float abv[8];
    #pragma unroll
    for (int n = 0; n < 8; ++n) abv[n] = Ab[n * 16 + l15];

    float sst[8], sq[8], rs[8];
    #pragma unroll
    for (int n = 0; n < 8; ++n) { sst[n] = 0.f; sq[n] = 0.f; rs[n] = 0.f; }

    const int mrow0 = w * 16 + lk * 4;
    #pragma unroll
    for (int r = 0; r < 4; ++r) {
        int row = mrow0 + r;
        int eid = eids[row], dn = dns[row], sn = sns[row];
        bool valid = (e0 + row) < E;
        s16x8 br8 = *reinterpret_cast<const s16x8*>(Bh + (size_t)dn * D + l15 * 8);
        s16x8 cr8 = *reinterpret_cast<const s16x8*>(Ch + (size_t)sn * D + l15 * 8);
        s16x8 vr8 = *reinterpret_cast<const s16x8*>(Vh + (size_t)sn * D + l15 * 8);
        if (valid) {
            f32x4 p0, p1;
            #pragma unroll
            for (int n = 0; n < 4; ++n) {
                p0[n] = acc[n][r] + abv[n]
                      + bf16_to_f32((ushort)br8[n]) + bf16_to_f32((ushort)cr8[n]);
                p1[n] = acc[n + 4][r] + abv[n + 4]
                      + bf16_to_f32((ushort)br8[n + 4]) + bf16_to_f32((ushort)cr8[n + 4]);
            }
            float* op = out_pre + (size_t)eid * D + l15 * 8;
            __builtin_nontemporal_store(p0, reinterpret_cast<f32x4*>(op));
            __builtin_nontemporal_store(p1, reinterpret_cast<f32x4*>(op + 4));
            #pragma unroll
            for (int n = 0; n < 4; ++n) {
                sst[n] += p0[n];     sq[n] += p0[n] * p0[n];
                sst[n + 4] += p1[n]; sq[n + 4] += p1[n] * p1[n];
            }
        }
        #pragma unroll
        for (int n = 0; n < 8; ++n) {
            float ein = bf16_to_f32(es[row * ESP + n * 16 + l15]);
            float m = valid ? bf16_to_f32((ushort)vr8[n]) / (1.f + __expf(-ein)) : 0.f;
            rs[n] += m;
        }
        bool flush = (r == 3) || (dns[row + 1] != dn);
        if (flush) {
            float* dst = out_h + (size_t)dn * D;
            #pragma unroll
            for (int n = 0; n < 8; ++n) {
                unsafeAtomicAdd(dst + n * 16 + l15, rs[n]);
                rs[n] = 0.f;
            }
        }
    }

    // stats: lanes l, l^16, l^32, l^48 share the same col set -> shfl reduce
    #pragma unroll
    for (int n = 0; n < 8; ++n) {
        sst[n] += __shfl_xor(sst[n], 16); sst[n] += __shfl_xor(sst[n], 32);
        sq[n]  += __shfl_xor(sq[n], 16);  sq[n]  += __shfl_xor(sq[n], 32);
    }
    if (l < 16) {
        #pragma unroll
        for (int n = 0; n < 8; ++n) {
            sbuf[w * 128 + n * 16 + l] = sst[n];
            qbuf[w * 128 + n * 16 + l] = sq[n];
        }
    }
    __syncthreads();
    if (tid < 128) {
        float ss = sbuf[tid] + sbuf[128 + tid] + sbuf[256 + tid] + sbuf[384 + tid];
        float qq = qbuf[tid] + qbuf[128 + tid] + qbuf[256 + tid] + qbuf[384 + tid];
        unsafeAtomicAdd(&e_sum[tid], ss);
        unsafeAtomicAdd(&e_sq[tid], qq);
    }
}

// ---------------- col stats over a [rows x 128] matrix (float4) ----------------
__global__ void col_stats_k(const float* __restrict__ X, int rows,
                            float* __restrict__ sum, float* __restrict__ sumsq)
{
    __shared__ float sr[8][128], qr[8][128];
    const int tx = threadIdx.x & 31;
    const int rp = threadIdx.x >> 5;
    float4 s = make_float4(0.f, 0.f, 0.f, 0.f);
    float4 q = make_float4(0.f, 0.f, 0.f, 0.f);
    for (int r = blockIdx.x * 8 + rp; r < rows; r += gridDim.x * 8) {
        float4 v = *reinterpret_cast<const float4*>(X + (size_t)r * D + 4 * tx);
        s.x += v.x; q.x += v.x * v.x;
        s.y += v.y; q.y += v.y * v.y;
        s.z += v.z; q.z += v.z * v.z;
        s.w += v.w; q.w += v.w * v.w;
    }
    *reinterpret_cast<float4*>(&sr[rp][4 * tx]) = s;
    *reinterpret_cast<float4*>(&qr[rp][4 * tx]) = q;
    __syncthreads();
    if (threadIdx.x < 128) {
        float ss = 0.f, qq = 0.f;
        #pragma unroll
        for (int t = 0; t < 8; ++t) { ss += sr[t][threadIdx.x]; qq += qr[t][threadIdx.x]; }
        unsafeAtomicAdd(&sum[threadIdx.x], ss);
        unsafeAtomicAdd(&sumsq[threadIdx.x], qq);
    }
}

// ---------------- finalize (natural layout, h-side) ----------------
__global__ void finalize_k(const float* __restrict__ res_in,
                           float* __restrict__ out,
                           const float* __restrict__ sum, const float* __restrict__ sumsq,
                           const float* __restrict__ gamma, const float* __restrict__ beta,
                           float cntInv, int rows)
{
    const int tx = threadIdx.x & 31;
    const int rp = threadIdx.x >> 5;
    const int col4 = 4 * tx;
    float mu[4], g[4], b[4];
    #pragma unroll
    for (int i = 0; i < 4; ++i) {
        float m = sum[col4 + i] * cntInv;
        float var = sumsq[col4 + i] * cntInv - m * m;
        mu[i] = m;
        g[i] = gamma[col4 + i] * rsqrtf(var + 1e-5f);
        b[i] = beta[col4 + i];
    }
    for (int r = blockIdx.x * 8 + rp; r < rows; r += gridDim.x * 8) {
        size_t o = (size_t)r * D + col4;
        float4 x = *reinterpret_cast<const float4*>(out + o);
        float4 rr = *reinterpret_cast<const float4*>(res_in + o);
        float4 y;
        y.x = rr.x + fmaxf(g[0] * (x.x - mu[0]) + b[0], 0.f);
        y.y = rr.y + fmaxf(g[1] * (x.y - mu[1]) + b[1], 0.f);
        y.z = rr.z + fmaxf(g[2] * (x.z - mu[2]) + b[2], 0.f);
        y.w = rr.w + fmaxf(g[3] * (x.w - mu[3]) + b[3], 0.f);
        *reinterpret_cast<float4*>(out + o) = y;
    }
}

// ---------------- finalize for PERMUTED pre (e-side, in-place) ----------------
__global__ void finalize_perm_k(const float* __restrict__ res_in,
                                float* out,
                                const float* __restrict__ sum, const float* __restrict__ sumsq,
                                const float* __restrict__ gamma, const float* __restrict__ beta,
                                float cntInv, int rows)
{
    const int tx = threadIdx.x & 31;
    const int rp = threadIdx.x >> 5;
    const int col4 = 4 * tx;
    float mu[4], g[4], b[4];
    #pragma unroll
    for (int i = 0; i < 4; ++i) {
        float m = sum[col4 + i] * cntInv;
        float var = sumsq[col4 + i] * cntInv - m * m;
        mu[i] = m;
        g[i] = gamma[col4 + i] * rsqrtf(var + 1e-5f);
        b[i] = beta[col4 + i];
    }
    for (int r = blockIdx.x * 8 + rp; r < rows; r += gridDim.x * 8) {
        size_t base = (size_t)r * D;
        float x[4];
        #pragma unroll
        for (int i = 0; i < 4; ++i) {
            int j = col4 + i;
            x[i] = out[base + (j & 15) * 8 + (j >> 4)];
        }
        float4 rr = *reinterpret_cast<const float4*>(res_in + base + col4);
        float4 y;
        y.x = rr.x + fmaxf(g[0] * (x[0] - mu[0]) + b[0], 0.f);
        y.y = rr.y + fmaxf(g[1] * (x[1] - mu[1]) + b[1], 0.f);
        y.z = rr.z + fmaxf(g[2] * (x[2] - mu[2]) + b[2], 0.f);
        y.w = rr.w + fmaxf(g[3] * (x[3] - mu[3]) + b[3], 0.f);
        *reinterpret_cast<float4*>(out + base + col4) = y;
    }
}

extern "C" void kernel_launch(void* const* d_in, const int* in_sizes, int n_in,
                              void* d_out, int out_size, void* d_ws, size_t ws_size,
                              hipStream_t stream)
{
    const float* h_in = (const float*)d_in[0];
    const float* e_in = (const float*)d_in[1];
    const int*   eidx = (const int*)d_in[2];
    const float* Uw = (const float*)d_in[3];  const float* Ub = (const float*)d_in[4];
    const float* Vw = (const float*)d_in[5];  const float* Vb = (const float*)d_in[6];
    const float* Aw = (const float*)d_in[7];  const float* Ab = (const float*)d_in[8];
    const float* Bw = (const float*)d_in[9];  const float* Bb = (const float*)d_in[10];
    const float* Cw = (const float*)d_in[11]; const float* Cb = (const float*)d_in[12];
    const float* hg = (const float*)d_in[13]; const float* hb = (const float*)d_in[14];
    const float* eg = (const float*)d_in[15]; const float* eb = (const float*)d_in[16];

    const int N = in_sizes[0] / D;
    const int E = in_sizes[1] / D;

    float* out_h = (float*)d_out;
    float* out_e = out_h + (size_t)N * D;   // holds permuted pre, then final

    ushort* Vh16 = (ushort*)d_ws;
    ushort* Bh16 = Vh16 + (size_t)N * D;
    ushort* Ch16 = Bh16 + (size_t)N * D;
    float* stats = (float*)(Ch16 + (size_t)N * D);
    float* h_sum = stats;       float* h_sq = stats + 128;
    float* e_sum = stats + 256; float* e_sq = stats + 384;
    int* deg    = (int*)(stats + 512);
    int* off    = deg + N;
    int* cursor = off + N + 1;
    int* perm   = cursor + N;
    ushort* Fh = (ushort*)(perm + E);        // 5*16384 ushort
    ushort* Fl = Fh + 5 * 16384;

    zero_misc_k<<<(N + 255) / 256, 256, 0, stream>>>(stats, deg, N);
    wconv5_k<<<(5 * 16384 + 255) / 256, 256, 0, stream>>>(Uw, Vw, Bw, Cw, Aw, Fh, Fl);
    hist_k<<<1024, 256, 0, stream>>>(eidx, deg, E);
    scan_k<<<1, 1024, 0, stream>>>(deg, off, cursor, N);
    scatter_k<<<1024, 256, 0, stream>>>(eidx, cursor, perm, E);
    node_linear_k<<<(N + TILE - 1) / TILE, 256, 0, stream>>>(
        h_in, Fh, Fl, Ub, Vb, Bb, Cb, out_h, Vh16, Bh16, Ch16, N);
    edge_k<<<(E + TILE - 1) / TILE, 256, 0, stream>>>(
        e_in, eidx, perm, Fh + 4 * 16384, Fl + 4 * 16384, Ab, Vh16, Bh16, Ch16,
        out_h, out_e, e_sum, e_sq, E);
    col_stats_k<<<256, 256, 0, stream>>>(out_h, N, h_sum, h_sq);
    finalize_k<<<256, 256, 0, stream>>>(h_in, out_h, h_sum, h_sq, hg, hb, 1.0f / (float)N, N);
    finalize_perm_k<<<2048, 256, 0, stream>>>(e_in, out_e, e_sum, e_sq, eg, eb, 1.0f / (float)E, E);
}